// Round 16
// baseline (17990.247 us; speedup 1.0000x reference)
//
#include <hip/hip_runtime.h>

#define NN 50000
#define EE 800000
#define DIN 128
#define DH 64
#define CC 4
#define LL 3

typedef float f32x16 __attribute__((ext_vector_type(16)));

__device__ __forceinline__ float sigmoidf_(float x) {
    return __builtin_amdgcn_rcpf(1.0f + __expf(-x));
}

// DPP quad_perm broadcast/permute (VALU-only cross-lane within groups of 4)
#define QPERM(x, CTRL) (__int_as_float(__builtin_amdgcn_update_dpp(0, __float_as_int(x), (CTRL), 0xF, 0xF, true)))
#define QB0 0x00
#define QROT 0x39    // quad_perm [1,2,3,0]: lane i <- lane (i+1)&3
#define QXOR1 0xB1   // [1,0,3,2]
#define QXOR2 0x4E   // [2,3,0,1]

// memory assembly kept as float4 loads; ALU ops are whole-vector expressions
// so the backend legalizes to v_pk_fma_f32.
#define LOAD16(V, P) { const float4* _p4 = (const float4*)(P); \
    float4 _a=_p4[0], _b=_p4[1], _c=_p4[2], _d=_p4[3]; \
    V[0]=_a.x; V[1]=_a.y; V[2]=_a.z; V[3]=_a.w; \
    V[4]=_b.x; V[5]=_b.y; V[6]=_b.z; V[7]=_b.w; \
    V[8]=_c.x; V[9]=_c.y; V[10]=_c.z; V[11]=_c.w; \
    V[12]=_d.x; V[13]=_d.y; V[14]=_d.z; V[15]=_d.w; }

#define ADD16(V, U) { V += (U); }
#define FMAV(V, W, xv) { V += (W) * (xv); }
#define MUL16(V, s) { V *= (s); }

#define SILU16(V) { \
    V[0]*=sigmoidf_(V[0]);  V[1]*=sigmoidf_(V[1]);  V[2]*=sigmoidf_(V[2]);  V[3]*=sigmoidf_(V[3]); \
    V[4]*=sigmoidf_(V[4]);  V[5]*=sigmoidf_(V[5]);  V[6]*=sigmoidf_(V[6]);  V[7]*=sigmoidf_(V[7]); \
    V[8]*=sigmoidf_(V[8]);  V[9]*=sigmoidf_(V[9]);  V[10]*=sigmoidf_(V[10]); V[11]*=sigmoidf_(V[11]); \
    V[12]*=sigmoidf_(V[12]); V[13]*=sigmoidf_(V[13]); V[14]*=sigmoidf_(V[14]); V[15]*=sigmoidf_(V[15]); }

#define DOTV(acc, V, W) { const f32x16 _m = (V) * (W); \
    acc += _m[0]+_m[1]+_m[2]+_m[3]+_m[4]+_m[5]+_m[6]+_m[7] \
         +_m[8]+_m[9]+_m[10]+_m[11]+_m[12]+_m[13]+_m[14]+_m[15]; }

#define SHFL16D(D, Ssrc, SS) { \
    D[0]=__shfl_down(Ssrc[0],SS);  D[1]=__shfl_down(Ssrc[1],SS); \
    D[2]=__shfl_down(Ssrc[2],SS);  D[3]=__shfl_down(Ssrc[3],SS); \
    D[4]=__shfl_down(Ssrc[4],SS);  D[5]=__shfl_down(Ssrc[5],SS); \
    D[6]=__shfl_down(Ssrc[6],SS);  D[7]=__shfl_down(Ssrc[7],SS); \
    D[8]=__shfl_down(Ssrc[8],SS);  D[9]=__shfl_down(Ssrc[9],SS); \
    D[10]=__shfl_down(Ssrc[10],SS); D[11]=__shfl_down(Ssrc[11],SS); \
    D[12]=__shfl_down(Ssrc[12],SS); D[13]=__shfl_down(Ssrc[13],SS); \
    D[14]=__shfl_down(Ssrc[14],SS); D[15]=__shfl_down(Ssrc[15],SS); }

// one GEMM k-step: weights row (runtime base), source element RR (literal)
// broadcast from quad lane 0.
#define WBL(WROW, RR, S0,S1,S2,S3, D0,D1,D2,D3) { f32x16 Wv; \
    LOAD16(Wv, (WROW) + (size_t)(RR)*DH) \
    { const float _m0=QPERM(S0[RR],QB0), _m1=QPERM(S1[RR],QB0), _m2=QPERM(S2[RR],QB0), _m3=QPERM(S3[RR],QB0); \
      FMAV(D0,Wv,_m0) FMAV(D1,Wv,_m1) FMAV(D2,Wv,_m2) FMAV(D3,Wv,_m3) } }

#define WBL16(WROW, S0,S1,S2,S3, D0,D1,D2,D3) \
    WBL(WROW,0, S0,S1,S2,S3,D0,D1,D2,D3)  WBL(WROW,1, S0,S1,S2,S3,D0,D1,D2,D3)  \
    WBL(WROW,2, S0,S1,S2,S3,D0,D1,D2,D3)  WBL(WROW,3, S0,S1,S2,S3,D0,D1,D2,D3)  \
    WBL(WROW,4, S0,S1,S2,S3,D0,D1,D2,D3)  WBL(WROW,5, S0,S1,S2,S3,D0,D1,D2,D3)  \
    WBL(WROW,6, S0,S1,S2,S3,D0,D1,D2,D3)  WBL(WROW,7, S0,S1,S2,S3,D0,D1,D2,D3)  \
    WBL(WROW,8, S0,S1,S2,S3,D0,D1,D2,D3)  WBL(WROW,9, S0,S1,S2,S3,D0,D1,D2,D3)  \
    WBL(WROW,10,S0,S1,S2,S3,D0,D1,D2,D3)  WBL(WROW,11,S0,S1,S2,S3,D0,D1,D2,D3)  \
    WBL(WROW,12,S0,S1,S2,S3,D0,D1,D2,D3)  WBL(WROW,13,S0,S1,S2,S3,D0,D1,D2,D3)  \
    WBL(WROW,14,S0,S1,S2,S3,D0,D1,D2,D3)  WBL(WROW,15,S0,S1,S2,S3,D0,D1,D2,D3)

// rotate a 16-vector across the quad: lane i <- lane (i+1)&3
#define ROT16(V) { \
    V[0]=QPERM(V[0],QROT);  V[1]=QPERM(V[1],QROT);  V[2]=QPERM(V[2],QROT);  V[3]=QPERM(V[3],QROT); \
    V[4]=QPERM(V[4],QROT);  V[5]=QPERM(V[5],QROT);  V[6]=QPERM(V[6],QROT);  V[7]=QPERM(V[7],QROT); \
    V[8]=QPERM(V[8],QROT);  V[9]=QPERM(V[9],QROT);  V[10]=QPERM(V[10],QROT); V[11]=QPERM(V[11],QROT); \
    V[12]=QPERM(V[12],QROT); V[13]=QPERM(V[13],QROT); V[14]=QPERM(V[14],QROT); V[15]=QPERM(V[15],QROT); }

// chain-scan combine step across quads (stride SS lanes)
#define SCANSTEP(SS) { \
    f32x16 bP; SHFL16D(bP, Pv, SS) \
    float bpx=__shfl_down(ppx,SS), bpy=__shfl_down(ppy,SS), bpz=__shfl_down(ppz,SS); \
    int   bhk=__shfl_down(hk,SS), btk=__shfl_down(tk,SS); \
    float bfl=__shfl_down(fullf,SS); \
    const bool vq = (wl + SS) < 64; \
    const float mt = (vq && (tk==bhk)) ? 1.0f : 0.0f; \
    const float ad = fullf*mt; \
    FMAV(Pv, bP, ad) ppx=fmaf(ad,bpx,ppx); ppy=fmaf(ad,bpy,ppy); ppz=fmaf(ad,bpz,ppz); \
    const float nf = fullf*bfl*mt; \
    fullf = vq ? nf : fullf; \
    tk    = vq ? btk : tk; }

// ---------------- degree count ----------------
__global__ void cnt_kernel(const int* __restrict__ dst, int* __restrict__ cnt, int E) {
    int e = blockIdx.x * 256 + threadIdx.x;
    if (e < E) atomicAdd(&cnt[dst[e]], 1);
}

// ---------------- scans ----------------
__global__ __launch_bounds__(256) void scan1(const int* __restrict__ cnt, int* __restrict__ offs,
                                             int* __restrict__ bsum, int N) {
    __shared__ int sh[256];
    int i = blockIdx.x * 256 + threadIdx.x;
    int v = (i < N) ? cnt[i] : 0;
    sh[threadIdx.x] = v; __syncthreads();
    for (int s = 1; s < 256; s <<= 1) {
        int a = (threadIdx.x >= s) ? sh[threadIdx.x - s] : 0;
        __syncthreads(); sh[threadIdx.x] += a; __syncthreads();
    }
    int incl = sh[threadIdx.x];
    if (i < N) offs[i] = incl - v;
    if (threadIdx.x == 255) bsum[blockIdx.x] = incl;
}
__global__ __launch_bounds__(256) void scan2(int* __restrict__ bsum, int nb) {
    __shared__ int sh[256];
    int v = (threadIdx.x < nb) ? bsum[threadIdx.x] : 0;
    sh[threadIdx.x] = v; __syncthreads();
    for (int s = 1; s < 256; s <<= 1) {
        int a = (threadIdx.x >= s) ? sh[threadIdx.x - s] : 0;
        __syncthreads(); sh[threadIdx.x] += a; __syncthreads();
    }
    if (threadIdx.x < nb) bsum[threadIdx.x] = sh[threadIdx.x] - v;
}
__global__ void scan3(int* __restrict__ offs, const int* __restrict__ bsum, int N) {
    int i = blockIdx.x * 256 + threadIdx.x;
    if (i < N) offs[i] += bsum[blockIdx.x];
}

// ---------------- counting-sort by dst ----------------
__global__ void order_kernel(const int* __restrict__ src, const int* __restrict__ dst,
                             const int* __restrict__ offs, int* __restrict__ fill,
                             int* __restrict__ ssrc, int* __restrict__ sdst, int E) {
    int e = blockIdx.x * 256 + threadIdx.x;
    if (e < E) {
        int d = dst[e];
        int slot = offs[d] + atomicAdd(&fill[d], 1);
        ssrc[slot] = src[e];
        sdst[slot] = d;
    }
}

// ---------------- fused_in: mix_in + pre (h, hsp, hdp for 8 nodes) ----------------
__global__ __launch_bounds__(256) void fused_in_kernel(
        const float* __restrict__ x, const float* __restrict__ Wmix,
        const float* __restrict__ ew1, const float* __restrict__ eb1,
        float* __restrict__ h, float* __restrict__ hsp, float* __restrict__ hdp,
        int N) {
    __shared__ float xs[8][DIN];       // 4 KB
    __shared__ float hs[8][CC * DH];   // 8 KB
    const int i0 = blockIdx.x * 8;
    const int tid = threadIdx.x;
    const int c = tid >> 6, d = tid & 63;

    for (int t = tid; t < 8 * DIN; t += 256) {
        int j = t / DIN, k = t % DIN;
        int i = i0 + j;
        xs[j][k] = (i < N) ? x[(size_t)i * DIN + k] : 0.f;
    }
    __syncthreads();

    float acc[8] = {0.f, 0.f, 0.f, 0.f, 0.f, 0.f, 0.f, 0.f};
    for (int k = 0; k < DIN; ++k) {
        float w = Wmix[k * (CC * DH) + tid];
        #pragma unroll
        for (int j = 0; j < 8; ++j) acc[j] += xs[j][k] * w;
    }
    #pragma unroll
    for (int j = 0; j < 8; ++j) {
        hs[j][tid] = acc[j];
        int i = i0 + j;
        if (i < N) h[((size_t)c * N + i) * DH + d] = acc[j];
    }
    __syncthreads();

    const float* W1 = ew1 + (size_t)c * (2 * DH + 1) * DH;
    float a_s[8] = {0.f, 0.f, 0.f, 0.f, 0.f, 0.f, 0.f, 0.f};
    float a_d[8] = {0.f, 0.f, 0.f, 0.f, 0.f, 0.f, 0.f, 0.f};
    #pragma unroll 4
    for (int k = 0; k < DH; ++k) {
        const float w_s = W1[(size_t)k * DH + d];
        const float w_d = W1[(size_t)(DH + k) * DH + d];
        #pragma unroll
        for (int j = 0; j < 8; ++j) {
            const float hv = hs[j][c * DH + k];
            a_s[j] += hv * w_s;
            a_d[j] += hv * w_d;
        }
    }
    const float b1 = eb1[(size_t)c * DH + d];
    #pragma unroll
    for (int j = 0; j < 8; ++j) {
        int i = i0 + j;
        if (i < N) {
            hsp[((size_t)c * N + i) * DH + d] = a_s[j];
            hdp[((size_t)c * N + i) * DH + d] = a_d[j] + b1;
        }
    }
}

// ---------------- edge kernel: quad decomposition, phase-looped GEMMs ----------------
__global__ __launch_bounds__(256, 2) void edge_kernel(
    const float* __restrict__ hsp, const float* __restrict__ hdp,
    const float* __restrict__ pos,
    const int* __restrict__ ssrc, const int* __restrict__ sdst,
    const float* __restrict__ ew1,
    const float* __restrict__ ew2, const float* __restrict__ eb2,
    const float* __restrict__ gw,  const float* __restrict__ gb,
    const float* __restrict__ pw1, const float* __restrict__ pb1,
    const float* __restrict__ pw2,
    float* __restrict__ agg, float* __restrict__ pos_acc,
    int E, int N)
{
    __shared__ float sW2[DH * DH];             // 16 KB
    __shared__ float sPW1[DH * DH];            // 16 KB
    __shared__ float sB2[DH], sPB1[DH], sGW[DH], sPW2[DH];

    const int ch = blockIdx.y;
    const int tid = threadIdx.x;

    {
        const float4* g2 = (const float4*)(ew2 + (size_t)ch * DH * DH);
        float4* l2 = (float4*)sW2;
        #pragma unroll
        for (int i = 0; i < 4; ++i) l2[tid + i * 256] = g2[tid + i * 256];
        const float4* g3 = (const float4*)(pw1 + (size_t)ch * DH * DH);
        float4* l3 = (float4*)sPW1;
        #pragma unroll
        for (int i = 0; i < 4; ++i) l3[tid + i * 256] = g3[tid + i * 256];
        if (tid < DH) {
            sB2[tid]  = eb2[(size_t)ch * DH + tid];
            sPB1[tid] = pb1[(size_t)ch * DH + tid];
            sGW[tid]  = gw[(size_t)ch * DH + tid];
            sPW2[tid] = pw2[(size_t)ch * DH + tid];
        }
    }
    __syncthreads();

    const int wl   = tid & 63;
    const int ck   = wl & 3;
    const int quad = wl >> 2;
    const int qedge = blockIdx.x * 256 + (tid >> 6) * 64 + quad * 4;

    f32x16 W128v;
    LOAD16(W128v, ew1 + (size_t)ch * (2 * DH + 1) * DH + (size_t)(2 * DH) * DH + ck * 16)

    const int4 s4 = *(const int4*)(ssrc + qedge);
    const int4 t4 = *(const int4*)(sdst + qedge);
    const int d_0 = t4.x, d_1 = t4.y, d_2 = t4.z, d_3 = t4.w;

    float rx0 = pos[3*s4.x+0]-pos[3*t4.x+0], ry0 = pos[3*s4.x+1]-pos[3*t4.x+1], rz0 = pos[3*s4.x+2]-pos[3*t4.x+2];
    float rx1 = pos[3*s4.y+0]-pos[3*t4.y+0], ry1 = pos[3*s4.y+1]-pos[3*t4.y+1], rz1 = pos[3*s4.y+2]-pos[3*t4.y+2];
    float rx2 = pos[3*s4.z+0]-pos[3*t4.z+0], ry2 = pos[3*s4.z+1]-pos[3*t4.z+1], rz2 = pos[3*s4.z+2]-pos[3*t4.z+2];
    float rx3 = pos[3*s4.w+0]-pos[3*t4.w+0], ry3 = pos[3*s4.w+1]-pos[3*t4.w+1], rz3 = pos[3*s4.w+2]-pos[3*t4.w+2];
    const float dd0 = rx0*rx0+ry0*ry0+rz0*rz0;
    const float dd1 = rx1*rx1+ry1*ry1+rz1*rz1;
    const float dd2 = rx2*rx2+ry2*ry2+rz2*rz2;
    const float dd3 = rx3*rx3+ry3*ry3+rz3*rz3;

    const float GB = gb[ch];
    const float* hsp_c = hsp + (size_t)ch * N * DH;
    const float* hdp_c = hdp + (size_t)ch * N * DH;

    // ---- m1 = silu(hsp[s] + hdp[t] + d2*w128) ----
    f32x16 A0, A1, A2, A3, T;
    LOAD16(A0, hsp_c + (size_t)s4.x * DH + ck*16)
    LOAD16(T,  hdp_c + (size_t)t4.x * DH + ck*16)  ADD16(A0, T)  FMAV(A0, W128v, dd0)
    LOAD16(A1, hsp_c + (size_t)s4.y * DH + ck*16)
    LOAD16(T,  hdp_c + (size_t)t4.y * DH + ck*16)  ADD16(A1, T)  FMAV(A1, W128v, dd1)
    LOAD16(A2, hsp_c + (size_t)s4.z * DH + ck*16)
    LOAD16(T,  hdp_c + (size_t)t4.z * DH + ck*16)  ADD16(A2, T)  FMAV(A2, W128v, dd2)
    LOAD16(A3, hsp_c + (size_t)s4.w * DH + ck*16)
    LOAD16(T,  hdp_c + (size_t)t4.w * DH + ck*16)  ADD16(A3, T)  FMAV(A3, W128v, dd3)
    SILU16(A0) SILU16(A1) SILU16(A2) SILU16(A3)

    // ---- m2 = silu(m1 @ W2 + B2) ----  (phase loop; sources quad-rotated; A dead after)
    f32x16 B0v, B1v, B2v, B3v;
    { f32x16 bz; LOAD16(bz, sB2 + ck*16) B0v = bz; B1v = bz; B2v = bz; B3v = bz; }
    #pragma unroll 1
    for (int p = 0; p < 4; ++p) {
        const float* wrow = sW2 + (size_t)(p * 16) * DH + ck * 16;
        WBL16(wrow, A0,A1,A2,A3, B0v,B1v,B2v,B3v)
        if (p < 3) { ROT16(A0) ROT16(A1) ROT16(A2) ROT16(A3) }
    }
    SILU16(B0v) SILU16(B1v) SILU16(B2v) SILU16(B3v)

    // ---- gate (quad reduce via DPP) ----
    {
        f32x16 GWv; LOAD16(GWv, sGW + ck*16)
        float g0 = 0.f, g1 = 0.f, g2 = 0.f, g3 = 0.f;
        DOTV(g0, B0v, GWv) DOTV(g1, B1v, GWv) DOTV(g2, B2v, GWv) DOTV(g3, B3v, GWv)
        g0 += QPERM(g0, QXOR1); g0 += QPERM(g0, QXOR2);
        g1 += QPERM(g1, QXOR1); g1 += QPERM(g1, QXOR2);
        g2 += QPERM(g2, QXOR1); g2 += QPERM(g2, QXOR2);
        g3 += QPERM(g3, QXOR1); g3 += QPERM(g3, QXOR2);
        const float ga0 = sigmoidf_(GB + g0), ga1 = sigmoidf_(GB + g1);
        const float ga2 = sigmoidf_(GB + g2), ga3 = sigmoidf_(GB + g3);
        MUL16(B0v, ga0) MUL16(B1v, ga1) MUL16(B2v, ga2) MUL16(B3v, ga3)
    }

    // ---- q = silu(m2 @ PW1 + PB1); p = q @ PW2 ----
    // phase loop; B rotated 4x -> restored to identity for the flush below.
    { f32x16 bz; LOAD16(bz, sPB1 + ck*16) A0 = bz; A1 = bz; A2 = bz; A3 = bz; }
    #pragma unroll 1
    for (int p = 0; p < 4; ++p) {
        const float* wrow = sPW1 + (size_t)(p * 16) * DH + ck * 16;
        WBL16(wrow, B0v,B1v,B2v,B3v, A0,A1,A2,A3)
        ROT16(B0v) ROT16(B1v) ROT16(B2v) ROT16(B3v)
    }
    SILU16(A0) SILU16(A1) SILU16(A2) SILU16(A3)
    float p0 = 0.f, p1 = 0.f, p2 = 0.f, p3 = 0.f;
    {
        f32x16 PW2v; LOAD16(PW2v, sPW2 + ck*16)
        DOTV(p0, A0, PW2v) DOTV(p1, A1, PW2v) DOTV(p2, A2, PW2v) DOTV(p3, A3, PW2v)
        p0 += QPERM(p0, QXOR1); p0 += QPERM(p0, QXOR2);
        p1 += QPERM(p1, QXOR1); p1 += QPERM(p1, QXOR2);
        p2 += QPERM(p2, QXOR1); p2 += QPERM(p2, QXOR2);
        p3 += QPERM(p3, QXOR1); p3 += QPERM(p3, QXOR2);
    }
    float tx0 = fminf(fmaxf(rx0*p0, -2.f), 2.f), ty0 = fminf(fmaxf(ry0*p0, -2.f), 2.f), tz0 = fminf(fmaxf(rz0*p0, -2.f), 2.f);
    float tx1 = fminf(fmaxf(rx1*p1, -2.f), 2.f), ty1 = fminf(fmaxf(ry1*p1, -2.f), 2.f), tz1 = fminf(fmaxf(rz1*p1, -2.f), 2.f);
    float tx2 = fminf(fmaxf(rx2*p2, -2.f), 2.f), ty2 = fminf(fmaxf(ry2*p2, -2.f), 2.f), tz2 = fminf(fmaxf(rz2*p2, -2.f), 2.f);
    float tx3 = fminf(fmaxf(rx3*p3, -2.f), 2.f), ty3 = fminf(fmaxf(ry3*p3, -2.f), 2.f), tz3 = fminf(fmaxf(rz3*p3, -2.f), 2.f);

    // ---- in-lane suffix merge over my 4 sorted edges ----
    const float e01 = (d_0 == d_1) ? 1.f : 0.f;
    const float e12 = (d_1 == d_2) ? 1.f : 0.f;
    const float e23 = (d_2 == d_3) ? 1.f : 0.f;
    FMAV(B2v, B3v, e23) tx2 = fmaf(e23, tx3, tx2); ty2 = fmaf(e23, ty3, ty2); tz2 = fmaf(e23, tz3, tz2);
    FMAV(B1v, B2v, e12) tx1 = fmaf(e12, tx2, tx1); ty1 = fmaf(e12, ty2, ty1); tz1 = fmaf(e12, tz2, tz1);
    FMAV(B0v, B1v, e01) tx0 = fmaf(e01, tx1, tx0); ty0 = fmaf(e01, ty1, ty0); tz0 = fmaf(e01, tz1, tz0);
    const float full0 = e01 * e12 * e23;
    const float f1 = e12 * e23;
    const float f2 = e23;

    // ---- cross-quad chain scan ----
    f32x16 Pv = B0v;
    float ppx = tx0, ppy = ty0, ppz = tz0;
    float fullf = full0;
    int hk = d_0, tk = d_3;
    SCANSTEP(4) SCANSTEP(8) SCANSTEP(16) SCANSTEP(32)
    f32x16 Sv; SHFL16D(Sv, Pv, 4)
    float spx = __shfl_down(ppx, 4), spy = __shfl_down(ppy, 4), spz = __shfl_down(ppz, 4);
    const int g1hk = __shfl_down(d_0, 4);
    const float sf = (((wl + 4) < 64) && (d_3 == g1hk)) ? 1.f : 0.f;
    MUL16(Sv, sf) spx *= sf; spy *= sf; spz *= sf;

    const int pd = __shfl_up(d_3, 4);
    const bool h0 = (quad == 0) || (pd != d_0);
    const bool h1 = (e01 == 0.f);
    const bool h2 = (e12 == 0.f);
    const bool h3 = (e23 == 0.f);

#define FLUSH(COND, DJ, BV, F, TX, TY, TZ) \
    if (COND) { \
        float* ar = agg + ((size_t)ch * N + (DJ)) * DH + ck * 16; \
        atomicAdd(ar+0,  BV[0]+(F)*Sv[0]);   atomicAdd(ar+1,  BV[1]+(F)*Sv[1]); \
        atomicAdd(ar+2,  BV[2]+(F)*Sv[2]);   atomicAdd(ar+3,  BV[3]+(F)*Sv[3]); \
        atomicAdd(ar+4,  BV[4]+(F)*Sv[4]);   atomicAdd(ar+5,  BV[5]+(F)*Sv[5]); \
        atomicAdd(ar+6,  BV[6]+(F)*Sv[6]);   atomicAdd(ar+7,  BV[7]+(F)*Sv[7]); \
        atomicAdd(ar+8,  BV[8]+(F)*Sv[8]);   atomicAdd(ar+9,  BV[9]+(F)*Sv[9]); \
        atomicAdd(ar+10, BV[10]+(F)*Sv[10]); atomicAdd(ar+11, BV[11]+(F)*Sv[11]); \
        atomicAdd(ar+12, BV[12]+(F)*Sv[12]); atomicAdd(ar+13, BV[13]+(F)*Sv[13]); \
        atomicAdd(ar+14, BV[14]+(F)*Sv[14]); atomicAdd(ar+15, BV[15]+(F)*Sv[15]); \
        if (ck == 0) { \
            atomicAdd(&pos_acc[(DJ)*3+0], (TX)+(F)*spx); \
            atomicAdd(&pos_acc[(DJ)*3+1], (TY)+(F)*spy); \
            atomicAdd(&pos_acc[(DJ)*3+2], (TZ)+(F)*spz); } }

    FLUSH(h0, d_0, B0v, full0, tx0, ty0, tz0)
    FLUSH(h1, d_1, B1v, f1,    tx1, ty1, tz1)
    FLUSH(h2, d_2, B2v, f2,    tx2, ty2, tz2)
    FLUSH(h3, d_3, B3v, 1.0f,  tx3, ty3, tz3)
#undef FLUSH
}

// ---------------- fused_out: node update + mix_out for 8 nodes ----------------
__global__ __launch_bounds__(256) void fused_out_kernel(
        const float* __restrict__ h, const float* __restrict__ agg,
        const float* __restrict__ nw, const float* __restrict__ nb,
        const float* __restrict__ Wout,
        float* __restrict__ x, int N) {
    __shared__ float hl[8][CC * DH];   // 8 KB
    __shared__ float al[8][CC * DH];   // 8 KB
    __shared__ float ol[8][CC * DH];   // 8 KB
    const int i0 = blockIdx.x * 8;
    const int tid = threadIdx.x;
    const int c = tid >> 6, d = tid & 63;

    for (int t = tid; t < 8 * CC * DH; t += 256) {
        int j = t >> 8, cd = t & 255;
        int cc = cd >> 6, dd = cd & 63;
        int i = i0 + j;
        if (i < N) {
            hl[j][cd] = h[((size_t)cc * N + i) * DH + dd];
            al[j][cd] = agg[((size_t)cc * N + i) * DH + dd];
        } else {
            hl[j][cd] = 0.f;
            al[j][cd] = 0.f;
        }
    }
    __syncthreads();

    {
        const float* W = nw + (size_t)c * (2 * DH) * DH;
        const float bn = nb[(size_t)c * DH + d];
        float acc[8] = {bn, bn, bn, bn, bn, bn, bn, bn};
        #pragma unroll 4
        for (int k = 0; k < DH; ++k) {
            const float w_h = W[(size_t)k * DH + d];
            const float w_a = W[(size_t)(DH + k) * DH + d];
            #pragma unroll
            for (int j = 0; j < 8; ++j) {
                acc[j] += hl[j][c * DH + k] * w_h + al[j][c * DH + k] * w_a;
            }
        }
        #pragma unroll
        for (int j = 0; j < 8; ++j) ol[j][tid] = acc[j];
    }
    __syncthreads();

    const int o = tid & 127, g = tid >> 7;
    float acc[4] = {0.f, 0.f, 0.f, 0.f};
    for (int cd = 0; cd < CC * DH; ++cd) {
        float w = Wout[(size_t)cd * DIN + o];
        #pragma unroll
        for (int j = 0; j < 4; ++j) acc[j] += ol[g * 4 + j][cd] * w;
    }
    #pragma unroll
    for (int j = 0; j < 4; ++j) {
        int i = i0 + g * 4 + j;
        if (i < N) x[(size_t)i * DIN + o] += acc[j];
    }
}

// ---------------- pos finalize ----------------
__global__ void pos_fin_kernel(float* __restrict__ pos, const float* __restrict__ pos_acc,
                               const int* __restrict__ cnt, int N) {
    int i = blockIdx.x * 256 + threadIdx.x;
    if (i < N) {
        float inv = 1.0f / ((float)CC * fmaxf((float)cnt[i], 1.0f));
        pos[i * 3 + 0] += pos_acc[i * 3 + 0] * inv;
        pos[i * 3 + 1] += pos_acc[i * 3 + 1] * inv;
        pos[i * 3 + 2] += pos_acc[i * 3 + 2] * inv;
    }
}

extern "C" void kernel_launch(void* const* d_in, const int* in_sizes, int n_in,
                              void* d_out, int out_size, void* d_ws, size_t ws_size,
                              hipStream_t stream) {
    const float* x         = (const float*)d_in[0];
    const float* pos       = (const float*)d_in[1];
    const int*   ei        = (const int*)d_in[2];
    const float* mix_in_w  = (const float*)d_in[3];
    const float* mix_out_w = (const float*)d_in[4];
    const float* ew1       = (const float*)d_in[5];
    const float* eb1       = (const float*)d_in[6];
    const float* ew2       = (const float*)d_in[7];
    const float* eb2       = (const float*)d_in[8];
    const float* gw        = (const float*)d_in[9];
    const float* gb        = (const float*)d_in[10];
    const float* nw        = (const float*)d_in[11];
    const float* nb        = (const float*)d_in[12];
    const float* pw1       = (const float*)d_in[13];
    const float* pb1       = (const float*)d_in[14];
    const float* pw2       = (const float*)d_in[15];

    const int* src = ei;
    const int* dst = ei + EE;

    float* xout    = (float*)d_out;
    float* pos_out = xout + (size_t)NN * DIN;

    float* hbuf    = (float*)d_ws;                     // C*N*64
    float* aggb    = hbuf + (size_t)CC * NN * DH;      // C*N*64
    float* hsp     = aggb + (size_t)CC * NN * DH;      // C*N*64
    float* hdp     = hsp  + (size_t)CC * NN * DH;      // C*N*64
    float* pos_cur = hdp  + (size_t)CC * NN * DH;      // N*3
    float* pos_acc = pos_cur + (size_t)NN * 3;         // N*3
    int*   cnt_i   = (int*)(pos_acc + (size_t)NN * 3); // N
    int*   offs    = cnt_i + NN;                       // N
    int*   fill    = offs + NN;                        // N
    int*   bsum    = fill + NN;                        // 256
    int*   ssrc    = bsum + 256;                       // E
    int*   sdst    = ssrc + EE;                        // E

    const int NB = (NN + 255) / 256;

    hipMemcpyAsync(xout, x, sizeof(float) * NN * DIN, hipMemcpyDeviceToDevice, stream);
    hipMemcpyAsync(pos_cur, pos, sizeof(float) * NN * 3, hipMemcpyDeviceToDevice, stream);
    hipMemsetAsync(cnt_i, 0, sizeof(int) * NN, stream);
    hipMemsetAsync(fill, 0, sizeof(int) * NN, stream);

    cnt_kernel<<<(EE + 255) / 256, 256, 0, stream>>>(dst, cnt_i, EE);
    scan1<<<NB, 256, 0, stream>>>(cnt_i, offs, bsum, NN);
    scan2<<<1, 256, 0, stream>>>(bsum, NB);
    scan3<<<NB, 256, 0, stream>>>(offs, bsum, NN);
    order_kernel<<<(EE + 255) / 256, 256, 0, stream>>>(src, dst, offs, fill, ssrc, sdst, EE);

    for (int l = 0; l < LL; ++l) {
        hipMemsetAsync(aggb, 0, sizeof(float) * CC * NN * DH, stream);
        hipMemsetAsync(pos_acc, 0, sizeof(float) * NN * 3, stream);

        fused_in_kernel<<<(NN + 7) / 8, 256, 0, stream>>>(
            xout, mix_in_w + (size_t)l * DIN * CC * DH,
            ew1 + (size_t)l * CC * (2 * DH + 1) * DH,
            eb1 + (size_t)l * CC * DH,
            hbuf, hsp, hdp, NN);

        edge_kernel<<<dim3(EE / 256, CC), 256, 0, stream>>>(
            hsp, hdp, pos_cur, ssrc, sdst,
            ew1 + (size_t)l * CC * (2 * DH + 1) * DH,
            ew2 + (size_t)l * CC * DH * DH,
            eb2 + (size_t)l * CC * DH,
            gw  + (size_t)l * CC * DH,
            gb  + (size_t)l * CC,
            pw1 + (size_t)l * CC * DH * DH,
            pb1 + (size_t)l * CC * DH,
            pw2 + (size_t)l * CC * DH,
            aggb, pos_acc, EE, NN);

        fused_out_kernel<<<(NN + 7) / 8, 256, 0, stream>>>(
            hbuf, aggb,
            nw + (size_t)l * CC * 2 * DH * DH,
            nb + (size_t)l * CC * DH,
            mix_out_w + (size_t)l * CC * DH * DIN,
            xout, NN);

        pos_fin_kernel<<<(NN + 255) / 256, 256, 0, stream>>>(pos_cur, pos_acc, cnt_i, NN);
    }

    hipMemcpyAsync(pos_out, pos_cur, sizeof(float) * NN * 3, hipMemcpyDeviceToDevice, stream);
}

// Round 17
// 5197.743 us; speedup vs baseline: 3.4612x; 3.4612x over previous
//
#include <hip/hip_runtime.h>

#define NN 50000
#define EE 800000
#define DIN 128
#define DH 64
#define CC 4
#define LL 3

typedef float f32x16 __attribute__((ext_vector_type(16)));

__device__ __forceinline__ float sigmoidf_(float x) {
    return __builtin_amdgcn_rcpf(1.0f + __expf(-x));
}

// DPP quad_perm broadcast/permute (VALU-only cross-lane within groups of 4)
#define QPERM(x, CTRL) (__int_as_float(__builtin_amdgcn_update_dpp(0, __float_as_int(x), (CTRL), 0xF, 0xF, true)))
#define QB0 0x00
#define QB1 0x55
#define QB2 0xAA
#define QB3 0xFF
#define QXOR1 0xB1   // [1,0,3,2]
#define QXOR2 0x4E   // [2,3,0,1]

// memory assembly kept as float4 loads (alignment-safe); ALU ops below are
// whole-vector expressions so the backend can legalize to v_pk_fma_f32.
#define LOAD16(V, P) { const float4* _p4 = (const float4*)(P); \
    float4 _a=_p4[0], _b=_p4[1], _c=_p4[2], _d=_p4[3]; \
    V[0]=_a.x; V[1]=_a.y; V[2]=_a.z; V[3]=_a.w; \
    V[4]=_b.x; V[5]=_b.y; V[6]=_b.z; V[7]=_b.w; \
    V[8]=_c.x; V[9]=_c.y; V[10]=_c.z; V[11]=_c.w; \
    V[12]=_d.x; V[13]=_d.y; V[14]=_d.z; V[15]=_d.w; }

#define ADD16(V, U) { V += (U); }
#define FMAV(V, W, xv) { V += (W) * (xv); }
#define MUL16(V, s) { V *= (s); }

#define SILU16(V) { \
    V[0]*=sigmoidf_(V[0]);  V[1]*=sigmoidf_(V[1]);  V[2]*=sigmoidf_(V[2]);  V[3]*=sigmoidf_(V[3]); \
    V[4]*=sigmoidf_(V[4]);  V[5]*=sigmoidf_(V[5]);  V[6]*=sigmoidf_(V[6]);  V[7]*=sigmoidf_(V[7]); \
    V[8]*=sigmoidf_(V[8]);  V[9]*=sigmoidf_(V[9]);  V[10]*=sigmoidf_(V[10]); V[11]*=sigmoidf_(V[11]); \
    V[12]*=sigmoidf_(V[12]); V[13]*=sigmoidf_(V[13]); V[14]*=sigmoidf_(V[14]); V[15]*=sigmoidf_(V[15]); }

#define DOTV(acc, V, W) { const f32x16 _m = (V) * (W); \
    acc += _m[0]+_m[1]+_m[2]+_m[3]+_m[4]+_m[5]+_m[6]+_m[7] \
         +_m[8]+_m[9]+_m[10]+_m[11]+_m[12]+_m[13]+_m[14]+_m[15]; }

#define SHFL16D(D, Ssrc, SS) { \
    D[0]=__shfl_down(Ssrc[0],SS);  D[1]=__shfl_down(Ssrc[1],SS); \
    D[2]=__shfl_down(Ssrc[2],SS);  D[3]=__shfl_down(Ssrc[3],SS); \
    D[4]=__shfl_down(Ssrc[4],SS);  D[5]=__shfl_down(Ssrc[5],SS); \
    D[6]=__shfl_down(Ssrc[6],SS);  D[7]=__shfl_down(Ssrc[7],SS); \
    D[8]=__shfl_down(Ssrc[8],SS);  D[9]=__shfl_down(Ssrc[9],SS); \
    D[10]=__shfl_down(Ssrc[10],SS); D[11]=__shfl_down(Ssrc[11],SS); \
    D[12]=__shfl_down(Ssrc[12],SS); D[13]=__shfl_down(Ssrc[13],SS); \
    D[14]=__shfl_down(Ssrc[14],SS); D[15]=__shfl_down(Ssrc[15],SS); }

// W2/PW1 k-step: DPP-broadcast source element r from quad lane of phase
#define WBK(WSRC, KK, QB, S0,S1,S2,S3, D0,D1,D2,D3, RR) { f32x16 Wv; \
    LOAD16(Wv, (WSRC) + (size_t)(KK)*DH + ck*16) \
    { const float _m0=QPERM(S0[RR],QB), _m1=QPERM(S1[RR],QB), _m2=QPERM(S2[RR],QB), _m3=QPERM(S3[RR],QB); \
      FMAV(D0,Wv,_m0) FMAV(D1,Wv,_m1) FMAV(D2,Wv,_m2) FMAV(D3,Wv,_m3) } }

#define WBPHASE(WSRC, P4, QB, S0,S1,S2,S3, D0,D1,D2,D3) \
    WBK(WSRC,(P4)*16+0, QB,S0,S1,S2,S3,D0,D1,D2,D3,0)  WBK(WSRC,(P4)*16+1, QB,S0,S1,S2,S3,D0,D1,D2,D3,1)  \
    WBK(WSRC,(P4)*16+2, QB,S0,S1,S2,S3,D0,D1,D2,D3,2)  WBK(WSRC,(P4)*16+3, QB,S0,S1,S2,S3,D0,D1,D2,D3,3)  \
    WBK(WSRC,(P4)*16+4, QB,S0,S1,S2,S3,D0,D1,D2,D3,4)  WBK(WSRC,(P4)*16+5, QB,S0,S1,S2,S3,D0,D1,D2,D3,5)  \
    WBK(WSRC,(P4)*16+6, QB,S0,S1,S2,S3,D0,D1,D2,D3,6)  WBK(WSRC,(P4)*16+7, QB,S0,S1,S2,S3,D0,D1,D2,D3,7)  \
    WBK(WSRC,(P4)*16+8, QB,S0,S1,S2,S3,D0,D1,D2,D3,8)  WBK(WSRC,(P4)*16+9, QB,S0,S1,S2,S3,D0,D1,D2,D3,9)  \
    WBK(WSRC,(P4)*16+10,QB,S0,S1,S2,S3,D0,D1,D2,D3,10) WBK(WSRC,(P4)*16+11,QB,S0,S1,S2,S3,D0,D1,D2,D3,11) \
    WBK(WSRC,(P4)*16+12,QB,S0,S1,S2,S3,D0,D1,D2,D3,12) WBK(WSRC,(P4)*16+13,QB,S0,S1,S2,S3,D0,D1,D2,D3,13) \
    WBK(WSRC,(P4)*16+14,QB,S0,S1,S2,S3,D0,D1,D2,D3,14) WBK(WSRC,(P4)*16+15,QB,S0,S1,S2,S3,D0,D1,D2,D3,15)

// chain-scan combine step across quads (stride SS lanes)
#define SCANSTEP(SS) { \
    f32x16 bP; SHFL16D(bP, Pv, SS) \
    float bpx=__shfl_down(ppx,SS), bpy=__shfl_down(ppy,SS), bpz=__shfl_down(ppz,SS); \
    int   bhk=__shfl_down(hk,SS), btk=__shfl_down(tk,SS); \
    float bfl=__shfl_down(fullf,SS); \
    const bool vq = (wl + SS) < 64; \
    const float mt = (vq && (tk==bhk)) ? 1.0f : 0.0f; \
    const float ad = fullf*mt; \
    FMAV(Pv, bP, ad) ppx=fmaf(ad,bpx,ppx); ppy=fmaf(ad,bpy,ppy); ppz=fmaf(ad,bpz,ppz); \
    const float nf = fullf*bfl*mt; \
    fullf = vq ? nf : fullf; \
    tk    = vq ? btk : tk; }

// ---------------- degree count ----------------
__global__ void cnt_kernel(const int* __restrict__ dst, int* __restrict__ cnt, int E) {
    int e = blockIdx.x * 256 + threadIdx.x;
    if (e < E) atomicAdd(&cnt[dst[e]], 1);
}

// ---------------- scans ----------------
__global__ __launch_bounds__(256) void scan1(const int* __restrict__ cnt, int* __restrict__ offs,
                                             int* __restrict__ bsum, int N) {
    __shared__ int sh[256];
    int i = blockIdx.x * 256 + threadIdx.x;
    int v = (i < N) ? cnt[i] : 0;
    sh[threadIdx.x] = v; __syncthreads();
    for (int s = 1; s < 256; s <<= 1) {
        int a = (threadIdx.x >= s) ? sh[threadIdx.x - s] : 0;
        __syncthreads(); sh[threadIdx.x] += a; __syncthreads();
    }
    int incl = sh[threadIdx.x];
    if (i < N) offs[i] = incl - v;
    if (threadIdx.x == 255) bsum[blockIdx.x] = incl;
}
__global__ __launch_bounds__(256) void scan2(int* __restrict__ bsum, int nb) {
    __shared__ int sh[256];
    int v = (threadIdx.x < nb) ? bsum[threadIdx.x] : 0;
    sh[threadIdx.x] = v; __syncthreads();
    for (int s = 1; s < 256; s <<= 1) {
        int a = (threadIdx.x >= s) ? sh[threadIdx.x - s] : 0;
        __syncthreads(); sh[threadIdx.x] += a; __syncthreads();
    }
    if (threadIdx.x < nb) bsum[threadIdx.x] = sh[threadIdx.x] - v;
}
__global__ void scan3(int* __restrict__ offs, const int* __restrict__ bsum, int N) {
    int i = blockIdx.x * 256 + threadIdx.x;
    if (i < N) offs[i] += bsum[blockIdx.x];
}

// ---------------- counting-sort by dst ----------------
__global__ void order_kernel(const int* __restrict__ src, const int* __restrict__ dst,
                             const int* __restrict__ offs, int* __restrict__ fill,
                             int* __restrict__ ssrc, int* __restrict__ sdst, int E) {
    int e = blockIdx.x * 256 + threadIdx.x;
    if (e < E) {
        int d = dst[e];
        int slot = offs[d] + atomicAdd(&fill[d], 1);
        ssrc[slot] = src[e];
        sdst[slot] = d;
    }
}

// ---------------- fused_in: mix_in + pre (h, hsp, hdp for 8 nodes) ----------------
__global__ __launch_bounds__(256) void fused_in_kernel(
        const float* __restrict__ x, const float* __restrict__ Wmix,
        const float* __restrict__ ew1, const float* __restrict__ eb1,
        float* __restrict__ h, float* __restrict__ hsp, float* __restrict__ hdp,
        int N) {
    __shared__ float xs[8][DIN];       // 4 KB
    __shared__ float hs[8][CC * DH];   // 8 KB
    const int i0 = blockIdx.x * 8;
    const int tid = threadIdx.x;
    const int c = tid >> 6, d = tid & 63;

    for (int t = tid; t < 8 * DIN; t += 256) {
        int j = t / DIN, k = t % DIN;
        int i = i0 + j;
        xs[j][k] = (i < N) ? x[(size_t)i * DIN + k] : 0.f;
    }
    __syncthreads();

    float acc[8] = {0.f, 0.f, 0.f, 0.f, 0.f, 0.f, 0.f, 0.f};
    for (int k = 0; k < DIN; ++k) {
        float w = Wmix[k * (CC * DH) + tid];
        #pragma unroll
        for (int j = 0; j < 8; ++j) acc[j] += xs[j][k] * w;
    }
    #pragma unroll
    for (int j = 0; j < 8; ++j) {
        hs[j][tid] = acc[j];
        int i = i0 + j;
        if (i < N) h[((size_t)c * N + i) * DH + d] = acc[j];
    }
    __syncthreads();

    const float* W1 = ew1 + (size_t)c * (2 * DH + 1) * DH;
    float a_s[8] = {0.f, 0.f, 0.f, 0.f, 0.f, 0.f, 0.f, 0.f};
    float a_d[8] = {0.f, 0.f, 0.f, 0.f, 0.f, 0.f, 0.f, 0.f};
    #pragma unroll 4
    for (int k = 0; k < DH; ++k) {
        const float w_s = W1[(size_t)k * DH + d];
        const float w_d = W1[(size_t)(DH + k) * DH + d];
        #pragma unroll
        for (int j = 0; j < 8; ++j) {
            const float hv = hs[j][c * DH + k];
            a_s[j] += hv * w_s;
            a_d[j] += hv * w_d;
        }
    }
    const float b1 = eb1[(size_t)c * DH + d];
    #pragma unroll
    for (int j = 0; j < 8; ++j) {
        int i = i0 + j;
        if (i < N) {
            hsp[((size_t)c * N + i) * DH + d] = a_s[j];
            hdp[((size_t)c * N + i) * DH + d] = a_d[j] + b1;
        }
    }
}

// ---------------- edge kernel: quad decomposition, precomputed W1 halves ----------------
__global__ __launch_bounds__(256, 2) void edge_kernel(
    const float* __restrict__ hsp, const float* __restrict__ hdp,
    const float* __restrict__ pos,
    const int* __restrict__ ssrc, const int* __restrict__ sdst,
    const float* __restrict__ ew1,
    const float* __restrict__ ew2, const float* __restrict__ eb2,
    const float* __restrict__ gw,  const float* __restrict__ gb,
    const float* __restrict__ pw1, const float* __restrict__ pb1,
    const float* __restrict__ pw2,
    float* __restrict__ agg, float* __restrict__ pos_acc,
    int E, int N)
{
    __shared__ float sW2[DH * DH];             // 16 KB
    __shared__ float sPW1[DH * DH];            // 16 KB
    __shared__ float sB2[DH], sPB1[DH], sGW[DH], sPW2[DH];

    const int ch = blockIdx.y;
    const int tid = threadIdx.x;

    {
        const float4* g2 = (const float4*)(ew2 + (size_t)ch * DH * DH);
        float4* l2 = (float4*)sW2;
        #pragma unroll
        for (int i = 0; i < 4; ++i) l2[tid + i * 256] = g2[tid + i * 256];
        const float4* g3 = (const float4*)(pw1 + (size_t)ch * DH * DH);
        float4* l3 = (float4*)sPW1;
        #pragma unroll
        for (int i = 0; i < 4; ++i) l3[tid + i * 256] = g3[tid + i * 256];
        if (tid < DH) {
            sB2[tid]  = eb2[(size_t)ch * DH + tid];
            sPB1[tid] = pb1[(size_t)ch * DH + tid];
            sGW[tid]  = gw[(size_t)ch * DH + tid];
            sPW2[tid] = pw2[(size_t)ch * DH + tid];
        }
    }
    __syncthreads();

    const int wl   = tid & 63;
    const int ck   = wl & 3;
    const int quad = wl >> 2;
    const int qedge = blockIdx.x * 256 + (tid >> 6) * 64 + quad * 4;

    f32x16 W128v;
    LOAD16(W128v, ew1 + (size_t)ch * (2 * DH + 1) * DH + (size_t)(2 * DH) * DH + ck * 16)

    const int4 s4 = *(const int4*)(ssrc + qedge);
    const int4 t4 = *(const int4*)(sdst + qedge);
    const int d_0 = t4.x, d_1 = t4.y, d_2 = t4.z, d_3 = t4.w;

    float rx0 = pos[3*s4.x+0]-pos[3*t4.x+0], ry0 = pos[3*s4.x+1]-pos[3*t4.x+1], rz0 = pos[3*s4.x+2]-pos[3*t4.x+2];
    float rx1 = pos[3*s4.y+0]-pos[3*t4.y+0], ry1 = pos[3*s4.y+1]-pos[3*t4.y+1], rz1 = pos[3*s4.y+2]-pos[3*t4.y+2];
    float rx2 = pos[3*s4.z+0]-pos[3*t4.z+0], ry2 = pos[3*s4.z+1]-pos[3*t4.z+1], rz2 = pos[3*s4.z+2]-pos[3*t4.z+2];
    float rx3 = pos[3*s4.w+0]-pos[3*t4.w+0], ry3 = pos[3*s4.w+1]-pos[3*t4.w+1], rz3 = pos[3*s4.w+2]-pos[3*t4.w+2];
    const float dd0 = rx0*rx0+ry0*ry0+rz0*rz0;
    const float dd1 = rx1*rx1+ry1*ry1+rz1*rz1;
    const float dd2 = rx2*rx2+ry2*ry2+rz2*rz2;
    const float dd3 = rx3*rx3+ry3*ry3+rz3*rz3;

    const float GB = gb[ch];
    const float* hsp_c = hsp + (size_t)ch * N * DH;
    const float* hdp_c = hdp + (size_t)ch * N * DH;

    // ---- m1 = silu(hsp[s] + hdp[t] + d2*w128) ----
    f32x16 A0, A1, A2, A3, T;
    LOAD16(A0, hsp_c + (size_t)s4.x * DH + ck*16)
    LOAD16(T,  hdp_c + (size_t)t4.x * DH + ck*16)  ADD16(A0, T)  FMAV(A0, W128v, dd0)
    LOAD16(A1, hsp_c + (size_t)s4.y * DH + ck*16)
    LOAD16(T,  hdp_c + (size_t)t4.y * DH + ck*16)  ADD16(A1, T)  FMAV(A1, W128v, dd1)
    LOAD16(A2, hsp_c + (size_t)s4.z * DH + ck*16)
    LOAD16(T,  hdp_c + (size_t)t4.z * DH + ck*16)  ADD16(A2, T)  FMAV(A2, W128v, dd2)
    LOAD16(A3, hsp_c + (size_t)s4.w * DH + ck*16)
    LOAD16(T,  hdp_c + (size_t)t4.w * DH + ck*16)  ADD16(A3, T)  FMAV(A3, W128v, dd3)
    SILU16(A0) SILU16(A1) SILU16(A2) SILU16(A3)

    // ---- m2 = silu(m1 @ W2 + B2) ----
    f32x16 B0v, B1v, B2v, B3v;
    { f32x16 bz; LOAD16(bz, sB2 + ck*16) B0v = bz; B1v = bz; B2v = bz; B3v = bz; }
    WBPHASE(sW2, 0, QB0, A0,A1,A2,A3, B0v,B1v,B2v,B3v)
    WBPHASE(sW2, 1, QB1, A0,A1,A2,A3, B0v,B1v,B2v,B3v)
    WBPHASE(sW2, 2, QB2, A0,A1,A2,A3, B0v,B1v,B2v,B3v)
    WBPHASE(sW2, 3, QB3, A0,A1,A2,A3, B0v,B1v,B2v,B3v)
    SILU16(B0v) SILU16(B1v) SILU16(B2v) SILU16(B3v)

    // ---- gate (quad reduce via DPP) ----
    {
        f32x16 GWv; LOAD16(GWv, sGW + ck*16)
        float g0 = 0.f, g1 = 0.f, g2 = 0.f, g3 = 0.f;
        DOTV(g0, B0v, GWv) DOTV(g1, B1v, GWv) DOTV(g2, B2v, GWv) DOTV(g3, B3v, GWv)
        g0 += QPERM(g0, QXOR1); g0 += QPERM(g0, QXOR2);
        g1 += QPERM(g1, QXOR1); g1 += QPERM(g1, QXOR2);
        g2 += QPERM(g2, QXOR1); g2 += QPERM(g2, QXOR2);
        g3 += QPERM(g3, QXOR1); g3 += QPERM(g3, QXOR2);
        const float ga0 = sigmoidf_(GB + g0), ga1 = sigmoidf_(GB + g1);
        const float ga2 = sigmoidf_(GB + g2), ga3 = sigmoidf_(GB + g3);
        MUL16(B0v, ga0) MUL16(B1v, ga1) MUL16(B2v, ga2) MUL16(B3v, ga3)
    }

    // ---- q = silu(m2 @ PW1 + PB1); p = q @ PW2 ----
    { f32x16 bz; LOAD16(bz, sPB1 + ck*16) A0 = bz; A1 = bz; A2 = bz; A3 = bz; }
    WBPHASE(sPW1, 0, QB0, B0v,B1v,B2v,B3v, A0,A1,A2,A3)
    WBPHASE(sPW1, 1, QB1, B0v,B1v,B2v,B3v, A0,A1,A2,A3)
    WBPHASE(sPW1, 2, QB2, B0v,B1v,B2v,B3v, A0,A1,A2,A3)
    WBPHASE(sPW1, 3, QB3, B0v,B1v,B2v,B3v, A0,A1,A2,A3)
    SILU16(A0) SILU16(A1) SILU16(A2) SILU16(A3)
    float p0 = 0.f, p1 = 0.f, p2 = 0.f, p3 = 0.f;
    {
        f32x16 PW2v; LOAD16(PW2v, sPW2 + ck*16)
        DOTV(p0, A0, PW2v) DOTV(p1, A1, PW2v) DOTV(p2, A2, PW2v) DOTV(p3, A3, PW2v)
        p0 += QPERM(p0, QXOR1); p0 += QPERM(p0, QXOR2);
        p1 += QPERM(p1, QXOR1); p1 += QPERM(p1, QXOR2);
        p2 += QPERM(p2, QXOR1); p2 += QPERM(p2, QXOR2);
        p3 += QPERM(p3, QXOR1); p3 += QPERM(p3, QXOR2);
    }
    float tx0 = fminf(fmaxf(rx0*p0, -2.f), 2.f), ty0 = fminf(fmaxf(ry0*p0, -2.f), 2.f), tz0 = fminf(fmaxf(rz0*p0, -2.f), 2.f);
    float tx1 = fminf(fmaxf(rx1*p1, -2.f), 2.f), ty1 = fminf(fmaxf(ry1*p1, -2.f), 2.f), tz1 = fminf(fmaxf(rz1*p1, -2.f), 2.f);
    float tx2 = fminf(fmaxf(rx2*p2, -2.f), 2.f), ty2 = fminf(fmaxf(ry2*p2, -2.f), 2.f), tz2 = fminf(fmaxf(rz2*p2, -2.f), 2.f);
    float tx3 = fminf(fmaxf(rx3*p3, -2.f), 2.f), ty3 = fminf(fmaxf(ry3*p3, -2.f), 2.f), tz3 = fminf(fmaxf(rz3*p3, -2.f), 2.f);

    // ---- in-lane suffix merge over my 4 sorted edges ----
    const float e01 = (d_0 == d_1) ? 1.f : 0.f;
    const float e12 = (d_1 == d_2) ? 1.f : 0.f;
    const float e23 = (d_2 == d_3) ? 1.f : 0.f;
    FMAV(B2v, B3v, e23) tx2 = fmaf(e23, tx3, tx2); ty2 = fmaf(e23, ty3, ty2); tz2 = fmaf(e23, tz3, tz2);
    FMAV(B1v, B2v, e12) tx1 = fmaf(e12, tx2, tx1); ty1 = fmaf(e12, ty2, ty1); tz1 = fmaf(e12, tz2, tz1);
    FMAV(B0v, B1v, e01) tx0 = fmaf(e01, tx1, tx0); ty0 = fmaf(e01, ty1, ty0); tz0 = fmaf(e01, tz1, tz0);
    const float full0 = e01 * e12 * e23;
    const float f1 = e12 * e23;
    const float f2 = e23;

    // ---- cross-quad chain scan ----
    f32x16 Pv = B0v;
    float ppx = tx0, ppy = ty0, ppz = tz0;
    float fullf = full0;
    int hk = d_0, tk = d_3;
    SCANSTEP(4) SCANSTEP(8) SCANSTEP(16) SCANSTEP(32)
    f32x16 Sv; SHFL16D(Sv, Pv, 4)
    float spx = __shfl_down(ppx, 4), spy = __shfl_down(ppy, 4), spz = __shfl_down(ppz, 4);
    const int g1hk = __shfl_down(d_0, 4);
    const float sf = (((wl + 4) < 64) && (d_3 == g1hk)) ? 1.f : 0.f;
    MUL16(Sv, sf) spx *= sf; spy *= sf; spz *= sf;

    const int pd = __shfl_up(d_3, 4);
    const bool h0 = (quad == 0) || (pd != d_0);
    const bool h1 = (e01 == 0.f);
    const bool h2 = (e12 == 0.f);
    const bool h3 = (e23 == 0.f);

#define FLUSH(COND, DJ, BV, F, TX, TY, TZ) \
    if (COND) { \
        float* ar = agg + ((size_t)ch * N + (DJ)) * DH + ck * 16; \
        atomicAdd(ar+0,  BV[0]+(F)*Sv[0]);   atomicAdd(ar+1,  BV[1]+(F)*Sv[1]); \
        atomicAdd(ar+2,  BV[2]+(F)*Sv[2]);   atomicAdd(ar+3,  BV[3]+(F)*Sv[3]); \
        atomicAdd(ar+4,  BV[4]+(F)*Sv[4]);   atomicAdd(ar+5,  BV[5]+(F)*Sv[5]); \
        atomicAdd(ar+6,  BV[6]+(F)*Sv[6]);   atomicAdd(ar+7,  BV[7]+(F)*Sv[7]); \
        atomicAdd(ar+8,  BV[8]+(F)*Sv[8]);   atomicAdd(ar+9,  BV[9]+(F)*Sv[9]); \
        atomicAdd(ar+10, BV[10]+(F)*Sv[10]); atomicAdd(ar+11, BV[11]+(F)*Sv[11]); \
        atomicAdd(ar+12, BV[12]+(F)*Sv[12]); atomicAdd(ar+13, BV[13]+(F)*Sv[13]); \
        atomicAdd(ar+14, BV[14]+(F)*Sv[14]); atomicAdd(ar+15, BV[15]+(F)*Sv[15]); \
        if (ck == 0) { \
            atomicAdd(&pos_acc[(DJ)*3+0], (TX)+(F)*spx); \
            atomicAdd(&pos_acc[(DJ)*3+1], (TY)+(F)*spy); \
            atomicAdd(&pos_acc[(DJ)*3+2], (TZ)+(F)*spz); } }

    FLUSH(h0, d_0, B0v, full0, tx0, ty0, tz0)
    FLUSH(h1, d_1, B1v, f1,    tx1, ty1, tz1)
    FLUSH(h2, d_2, B2v, f2,    tx2, ty2, tz2)
    FLUSH(h3, d_3, B3v, 1.0f,  tx3, ty3, tz3)
#undef FLUSH
}

// ---------------- fused_out: node update + mix_out for 8 nodes ----------------
__global__ __launch_bounds__(256) void fused_out_kernel(
        const float* __restrict__ h, const float* __restrict__ agg,
        const float* __restrict__ nw, const float* __restrict__ nb,
        const float* __restrict__ Wout,
        float* __restrict__ x, int N) {
    __shared__ float hl[8][CC * DH];   // 8 KB
    __shared__ float al[8][CC * DH];   // 8 KB
    __shared__ float ol[8][CC * DH];   // 8 KB
    const int i0 = blockIdx.x * 8;
    const int tid = threadIdx.x;
    const int c = tid >> 6, d = tid & 63;

    for (int t = tid; t < 8 * CC * DH; t += 256) {
        int j = t >> 8, cd = t & 255;
        int cc = cd >> 6, dd = cd & 63;
        int i = i0 + j;
        if (i < N) {
            hl[j][cd] = h[((size_t)cc * N + i) * DH + dd];
            al[j][cd] = agg[((size_t)cc * N + i) * DH + dd];
        } else {
            hl[j][cd] = 0.f;
            al[j][cd] = 0.f;
        }
    }
    __syncthreads();

    {
        const float* W = nw + (size_t)c * (2 * DH) * DH;
        const float bn = nb[(size_t)c * DH + d];
        float acc[8] = {bn, bn, bn, bn, bn, bn, bn, bn};
        #pragma unroll 4
        for (int k = 0; k < DH; ++k) {
            const float w_h = W[(size_t)k * DH + d];
            const float w_a = W[(size_t)(DH + k) * DH + d];
            #pragma unroll
            for (int j = 0; j < 8; ++j) {
                acc[j] += hl[j][c * DH + k] * w_h + al[j][c * DH + k] * w_a;
            }
        }
        #pragma unroll
        for (int j = 0; j < 8; ++j) ol[j][tid] = acc[j];
    }
    __syncthreads();

    const int o = tid & 127, g = tid >> 7;
    float acc[4] = {0.f, 0.f, 0.f, 0.f};
    for (int cd = 0; cd < CC * DH; ++cd) {
        float w = Wout[(size_t)cd * DIN + o];
        #pragma unroll
        for (int j = 0; j < 4; ++j) acc[j] += ol[g * 4 + j][cd] * w;
    }
    #pragma unroll
    for (int j = 0; j < 4; ++j) {
        int i = i0 + g * 4 + j;
        if (i < N) x[(size_t)i * DIN + o] += acc[j];
    }
}

// ---------------- pos finalize ----------------
__global__ void pos_fin_kernel(float* __restrict__ pos, const float* __restrict__ pos_acc,
                               const int* __restrict__ cnt, int N) {
    int i = blockIdx.x * 256 + threadIdx.x;
    if (i < N) {
        float inv = 1.0f / ((float)CC * fmaxf((float)cnt[i], 1.0f));
        pos[i * 3 + 0] += pos_acc[i * 3 + 0] * inv;
        pos[i * 3 + 1] += pos_acc[i * 3 + 1] * inv;
        pos[i * 3 + 2] += pos_acc[i * 3 + 2] * inv;
    }
}

extern "C" void kernel_launch(void* const* d_in, const int* in_sizes, int n_in,
                              void* d_out, int out_size, void* d_ws, size_t ws_size,
                              hipStream_t stream) {
    const float* x         = (const float*)d_in[0];
    const float* pos       = (const float*)d_in[1];
    const int*   ei        = (const int*)d_in[2];
    const float* mix_in_w  = (const float*)d_in[3];
    const float* mix_out_w = (const float*)d_in[4];
    const float* ew1       = (const float*)d_in[5];
    const float* eb1       = (const float*)d_in[6];
    const float* ew2       = (const float*)d_in[7];
    const float* eb2       = (const float*)d_in[8];
    const float* gw        = (const float*)d_in[9];
    const float* gb        = (const float*)d_in[10];
    const float* nw        = (const float*)d_in[11];
    const float* nb        = (const float*)d_in[12];
    const float* pw1       = (const float*)d_in[13];
    const float* pb1       = (const float*)d_in[14];
    const float* pw2       = (const float*)d_in[15];

    const int* src = ei;
    const int* dst = ei + EE;

    float* xout    = (float*)d_out;
    float* pos_out = xout + (size_t)NN * DIN;

    float* hbuf    = (float*)d_ws;                     // C*N*64
    float* aggb    = hbuf + (size_t)CC * NN * DH;      // C*N*64
    float* hsp     = aggb + (size_t)CC * NN * DH;      // C*N*64
    float* hdp     = hsp  + (size_t)CC * NN * DH;      // C*N*64
    float* pos_cur = hdp  + (size_t)CC * NN * DH;      // N*3
    float* pos_acc = pos_cur + (size_t)NN * 3;         // N*3
    int*   cnt_i   = (int*)(pos_acc + (size_t)NN * 3); // N
    int*   offs    = cnt_i + NN;                       // N
    int*   fill    = offs + NN;                        // N
    int*   bsum    = fill + NN;                        // 256
    int*   ssrc    = bsum + 256;                       // E
    int*   sdst    = ssrc + EE;                        // E

    const int NB = (NN + 255) / 256;

    hipMemcpyAsync(xout, x, sizeof(float) * NN * DIN, hipMemcpyDeviceToDevice, stream);
    hipMemcpyAsync(pos_cur, pos, sizeof(float) * NN * 3, hipMemcpyDeviceToDevice, stream);
    hipMemsetAsync(cnt_i, 0, sizeof(int) * NN, stream);
    hipMemsetAsync(fill, 0, sizeof(int) * NN, stream);

    cnt_kernel<<<(EE + 255) / 256, 256, 0, stream>>>(dst, cnt_i, EE);
    scan1<<<NB, 256, 0, stream>>>(cnt_i, offs, bsum, NN);
    scan2<<<1, 256, 0, stream>>>(bsum, NB);
    scan3<<<NB, 256, 0, stream>>>(offs, bsum, NN);
    order_kernel<<<(EE + 255) / 256, 256, 0, stream>>>(src, dst, offs, fill, ssrc, sdst, EE);

    for (int l = 0; l < LL; ++l) {
        hipMemsetAsync(aggb, 0, sizeof(float) * CC * NN * DH, stream);
        hipMemsetAsync(pos_acc, 0, sizeof(float) * NN * 3, stream);

        fused_in_kernel<<<(NN + 7) / 8, 256, 0, stream>>>(
            xout, mix_in_w + (size_t)l * DIN * CC * DH,
            ew1 + (size_t)l * CC * (2 * DH + 1) * DH,
            eb1 + (size_t)l * CC * DH,
            hbuf, hsp, hdp, NN);

        edge_kernel<<<dim3(EE / 256, CC), 256, 0, stream>>>(
            hsp, hdp, pos_cur, ssrc, sdst,
            ew1 + (size_t)l * CC * (2 * DH + 1) * DH,
            ew2 + (size_t)l * CC * DH * DH,
            eb2 + (size_t)l * CC * DH,
            gw  + (size_t)l * CC * DH,
            gb  + (size_t)l * CC,
            pw1 + (size_t)l * CC * DH * DH,
            pb1 + (size_t)l * CC * DH,
            pw2 + (size_t)l * CC * DH,
            aggb, pos_acc, EE, NN);

        fused_out_kernel<<<(NN + 7) / 8, 256, 0, stream>>>(
            hbuf, aggb,
            nw + (size_t)l * CC * 2 * DH * DH,
            nb + (size_t)l * CC * DH,
            mix_out_w + (size_t)l * CC * DH * DIN,
            xout, NN);

        pos_fin_kernel<<<(NN + 255) / 256, 256, 0, stream>>>(pos_cur, pos_acc, cnt_i, NN);
    }

    hipMemcpyAsync(pos_out, pos_cur, sizeof(float) * NN * 3, hipMemcpyDeviceToDevice, stream);
}

// Round 18
// 5195.826 us; speedup vs baseline: 3.4624x; 1.0004x over previous
//
#include <hip/hip_runtime.h>

#define NN 50000
#define EE 800000
#define DIN 128
#define DH 64
#define CC 4
#define LL 3

typedef float f32x16 __attribute__((ext_vector_type(16)));

__device__ __forceinline__ float sigmoidf_(float x) {
    return __builtin_amdgcn_rcpf(1.0f + __expf(-x));
}

// DPP quad_perm broadcast/permute (VALU-only cross-lane within groups of 4)
#define QPERM(x, CTRL) (__int_as_float(__builtin_amdgcn_update_dpp(0, __float_as_int(x), (CTRL), 0xF, 0xF, true)))
#define QB0 0x00
#define QB1 0x55
#define QB2 0xAA
#define QB3 0xFF
#define QXOR1 0xB1   // [1,0,3,2]
#define QXOR2 0x4E   // [2,3,0,1]

// memory assembly kept as float4 loads (alignment-safe); ALU ops below are
// whole-vector expressions so the backend can legalize to v_pk_fma_f32.
#define LOAD16(V, P) { const float4* _p4 = (const float4*)(P); \
    float4 _a=_p4[0], _b=_p4[1], _c=_p4[2], _d=_p4[3]; \
    V[0]=_a.x; V[1]=_a.y; V[2]=_a.z; V[3]=_a.w; \
    V[4]=_b.x; V[5]=_b.y; V[6]=_b.z; V[7]=_b.w; \
    V[8]=_c.x; V[9]=_c.y; V[10]=_c.z; V[11]=_c.w; \
    V[12]=_d.x; V[13]=_d.y; V[14]=_d.z; V[15]=_d.w; }

#define ADD16(V, U) { V += (U); }
#define FMAV(V, W, xv) { V += (W) * (xv); }
#define MUL16(V, s) { V *= (s); }

#define SILU16(V) { \
    V[0]*=sigmoidf_(V[0]);  V[1]*=sigmoidf_(V[1]);  V[2]*=sigmoidf_(V[2]);  V[3]*=sigmoidf_(V[3]); \
    V[4]*=sigmoidf_(V[4]);  V[5]*=sigmoidf_(V[5]);  V[6]*=sigmoidf_(V[6]);  V[7]*=sigmoidf_(V[7]); \
    V[8]*=sigmoidf_(V[8]);  V[9]*=sigmoidf_(V[9]);  V[10]*=sigmoidf_(V[10]); V[11]*=sigmoidf_(V[11]); \
    V[12]*=sigmoidf_(V[12]); V[13]*=sigmoidf_(V[13]); V[14]*=sigmoidf_(V[14]); V[15]*=sigmoidf_(V[15]); }

#define DOTV(acc, V, W) { const f32x16 _m = (V) * (W); \
    acc += _m[0]+_m[1]+_m[2]+_m[3]+_m[4]+_m[5]+_m[6]+_m[7] \
         +_m[8]+_m[9]+_m[10]+_m[11]+_m[12]+_m[13]+_m[14]+_m[15]; }

#define SHFL16D(D, Ssrc, SS) { \
    D[0]=__shfl_down(Ssrc[0],SS);  D[1]=__shfl_down(Ssrc[1],SS); \
    D[2]=__shfl_down(Ssrc[2],SS);  D[3]=__shfl_down(Ssrc[3],SS); \
    D[4]=__shfl_down(Ssrc[4],SS);  D[5]=__shfl_down(Ssrc[5],SS); \
    D[6]=__shfl_down(Ssrc[6],SS);  D[7]=__shfl_down(Ssrc[7],SS); \
    D[8]=__shfl_down(Ssrc[8],SS);  D[9]=__shfl_down(Ssrc[9],SS); \
    D[10]=__shfl_down(Ssrc[10],SS); D[11]=__shfl_down(Ssrc[11],SS); \
    D[12]=__shfl_down(Ssrc[12],SS); D[13]=__shfl_down(Ssrc[13],SS); \
    D[14]=__shfl_down(Ssrc[14],SS); D[15]=__shfl_down(Ssrc[15],SS); }

// W2/PW1 k-step: DPP-broadcast source element r from quad lane of phase
#define WBK(WSRC, KK, QB, S0,S1,S2,S3, D0,D1,D2,D3, RR) { f32x16 Wv; \
    LOAD16(Wv, (WSRC) + (size_t)(KK)*DH + ck*16) \
    { const float _m0=QPERM(S0[RR],QB), _m1=QPERM(S1[RR],QB), _m2=QPERM(S2[RR],QB), _m3=QPERM(S3[RR],QB); \
      FMAV(D0,Wv,_m0) FMAV(D1,Wv,_m1) FMAV(D2,Wv,_m2) FMAV(D3,Wv,_m3) } }

#define WBPHASE(WSRC, P4, QB, S0,S1,S2,S3, D0,D1,D2,D3) \
    WBK(WSRC,(P4)*16+0, QB,S0,S1,S2,S3,D0,D1,D2,D3,0)  WBK(WSRC,(P4)*16+1, QB,S0,S1,S2,S3,D0,D1,D2,D3,1)  \
    WBK(WSRC,(P4)*16+2, QB,S0,S1,S2,S3,D0,D1,D2,D3,2)  WBK(WSRC,(P4)*16+3, QB,S0,S1,S2,S3,D0,D1,D2,D3,3)  \
    WBK(WSRC,(P4)*16+4, QB,S0,S1,S2,S3,D0,D1,D2,D3,4)  WBK(WSRC,(P4)*16+5, QB,S0,S1,S2,S3,D0,D1,D2,D3,5)  \
    WBK(WSRC,(P4)*16+6, QB,S0,S1,S2,S3,D0,D1,D2,D3,6)  WBK(WSRC,(P4)*16+7, QB,S0,S1,S2,S3,D0,D1,D2,D3,7)  \
    WBK(WSRC,(P4)*16+8, QB,S0,S1,S2,S3,D0,D1,D2,D3,8)  WBK(WSRC,(P4)*16+9, QB,S0,S1,S2,S3,D0,D1,D2,D3,9)  \
    WBK(WSRC,(P4)*16+10,QB,S0,S1,S2,S3,D0,D1,D2,D3,10) WBK(WSRC,(P4)*16+11,QB,S0,S1,S2,S3,D0,D1,D2,D3,11) \
    WBK(WSRC,(P4)*16+12,QB,S0,S1,S2,S3,D0,D1,D2,D3,12) WBK(WSRC,(P4)*16+13,QB,S0,S1,S2,S3,D0,D1,D2,D3,13) \
    WBK(WSRC,(P4)*16+14,QB,S0,S1,S2,S3,D0,D1,D2,D3,14) WBK(WSRC,(P4)*16+15,QB,S0,S1,S2,S3,D0,D1,D2,D3,15)

// chain-scan combine step across quads (stride SS lanes)
#define SCANSTEP(SS) { \
    f32x16 bP; SHFL16D(bP, Pv, SS) \
    float bpx=__shfl_down(ppx,SS), bpy=__shfl_down(ppy,SS), bpz=__shfl_down(ppz,SS); \
    int   bhk=__shfl_down(hk,SS), btk=__shfl_down(tk,SS); \
    float bfl=__shfl_down(fullf,SS); \
    const bool vq = (wl + SS) < 64; \
    const float mt = (vq && (tk==bhk)) ? 1.0f : 0.0f; \
    const float ad = fullf*mt; \
    FMAV(Pv, bP, ad) ppx=fmaf(ad,bpx,ppx); ppy=fmaf(ad,bpy,ppy); ppz=fmaf(ad,bpz,ppz); \
    const float nf = fullf*bfl*mt; \
    fullf = vq ? nf : fullf; \
    tk    = vq ? btk : tk; }

// ---------------- degree count ----------------
__global__ void cnt_kernel(const int* __restrict__ dst, int* __restrict__ cnt, int E) {
    int e = blockIdx.x * 256 + threadIdx.x;
    if (e < E) atomicAdd(&cnt[dst[e]], 1);
}

// ---------------- scans ----------------
__global__ __launch_bounds__(256) void scan1(const int* __restrict__ cnt, int* __restrict__ offs,
                                             int* __restrict__ bsum, int N) {
    __shared__ int sh[256];
    int i = blockIdx.x * 256 + threadIdx.x;
    int v = (i < N) ? cnt[i] : 0;
    sh[threadIdx.x] = v; __syncthreads();
    for (int s = 1; s < 256; s <<= 1) {
        int a = (threadIdx.x >= s) ? sh[threadIdx.x - s] : 0;
        __syncthreads(); sh[threadIdx.x] += a; __syncthreads();
    }
    int incl = sh[threadIdx.x];
    if (i < N) offs[i] = incl - v;
    if (threadIdx.x == 255) bsum[blockIdx.x] = incl;
}
__global__ __launch_bounds__(256) void scan2(int* __restrict__ bsum, int nb) {
    __shared__ int sh[256];
    int v = (threadIdx.x < nb) ? bsum[threadIdx.x] : 0;
    sh[threadIdx.x] = v; __syncthreads();
    for (int s = 1; s < 256; s <<= 1) {
        int a = (threadIdx.x >= s) ? sh[threadIdx.x - s] : 0;
        __syncthreads(); sh[threadIdx.x] += a; __syncthreads();
    }
    if (threadIdx.x < nb) bsum[threadIdx.x] = sh[threadIdx.x] - v;
}
__global__ void scan3(int* __restrict__ offs, const int* __restrict__ bsum, int N) {
    int i = blockIdx.x * 256 + threadIdx.x;
    if (i < N) offs[i] += bsum[blockIdx.x];
}

// ---------------- counting-sort by dst ----------------
__global__ void order_kernel(const int* __restrict__ src, const int* __restrict__ dst,
                             const int* __restrict__ offs, int* __restrict__ fill,
                             int* __restrict__ ssrc, int* __restrict__ sdst, int E) {
    int e = blockIdx.x * 256 + threadIdx.x;
    if (e < E) {
        int d = dst[e];
        int slot = offs[d] + atomicAdd(&fill[d], 1);
        ssrc[slot] = src[e];
        sdst[slot] = d;
    }
}

// ---------------- fused_in: mix_in + pre (h, hsp, hdp for 8 nodes) ----------------
__global__ __launch_bounds__(256) void fused_in_kernel(
        const float* __restrict__ x, const float* __restrict__ Wmix,
        const float* __restrict__ ew1, const float* __restrict__ eb1,
        float* __restrict__ h, float* __restrict__ hsp, float* __restrict__ hdp,
        int N) {
    __shared__ float xs[8][DIN];       // 4 KB
    __shared__ float hs[8][CC * DH];   // 8 KB
    const int i0 = blockIdx.x * 8;
    const int tid = threadIdx.x;
    const int c = tid >> 6, d = tid & 63;

    for (int t = tid; t < 8 * DIN; t += 256) {
        int j = t / DIN, k = t % DIN;
        int i = i0 + j;
        xs[j][k] = (i < N) ? x[(size_t)i * DIN + k] : 0.f;
    }
    __syncthreads();

    float acc[8] = {0.f, 0.f, 0.f, 0.f, 0.f, 0.f, 0.f, 0.f};
    for (int k = 0; k < DIN; ++k) {
        float w = Wmix[k * (CC * DH) + tid];
        #pragma unroll
        for (int j = 0; j < 8; ++j) acc[j] += xs[j][k] * w;
    }
    #pragma unroll
    for (int j = 0; j < 8; ++j) {
        hs[j][tid] = acc[j];
        int i = i0 + j;
        if (i < N) h[((size_t)c * N + i) * DH + d] = acc[j];
    }
    __syncthreads();

    const float* W1 = ew1 + (size_t)c * (2 * DH + 1) * DH;
    float a_s[8] = {0.f, 0.f, 0.f, 0.f, 0.f, 0.f, 0.f, 0.f};
    float a_d[8] = {0.f, 0.f, 0.f, 0.f, 0.f, 0.f, 0.f, 0.f};
    #pragma unroll 4
    for (int k = 0; k < DH; ++k) {
        const float w_s = W1[(size_t)k * DH + d];
        const float w_d = W1[(size_t)(DH + k) * DH + d];
        #pragma unroll
        for (int j = 0; j < 8; ++j) {
            const float hv = hs[j][c * DH + k];
            a_s[j] += hv * w_s;
            a_d[j] += hv * w_d;
        }
    }
    const float b1 = eb1[(size_t)c * DH + d];
    #pragma unroll
    for (int j = 0; j < 8; ++j) {
        int i = i0 + j;
        if (i < N) {
            hsp[((size_t)c * N + i) * DH + d] = a_s[j];
            hdp[((size_t)c * N + i) * DH + d] = a_d[j] + b1;
        }
    }
}

// ---------------- edge kernel: quad decomposition, precomputed W1 halves ----------------
// NOTE: no waves-per-eu arg — testing whether (,2) was capping residency at 2 waves/SIMD.
__global__ __launch_bounds__(256) void edge_kernel(
    const float* __restrict__ hsp, const float* __restrict__ hdp,
    const float* __restrict__ pos,
    const int* __restrict__ ssrc, const int* __restrict__ sdst,
    const float* __restrict__ ew1,
    const float* __restrict__ ew2, const float* __restrict__ eb2,
    const float* __restrict__ gw,  const float* __restrict__ gb,
    const float* __restrict__ pw1, const float* __restrict__ pb1,
    const float* __restrict__ pw2,
    float* __restrict__ agg, float* __restrict__ pos_acc,
    int E, int N)
{
    __shared__ float sW2[DH * DH];             // 16 KB
    __shared__ float sPW1[DH * DH];            // 16 KB
    __shared__ float sB2[DH], sPB1[DH], sGW[DH], sPW2[DH];

    const int ch = blockIdx.y;
    const int tid = threadIdx.x;

    {
        const float4* g2 = (const float4*)(ew2 + (size_t)ch * DH * DH);
        float4* l2 = (float4*)sW2;
        #pragma unroll
        for (int i = 0; i < 4; ++i) l2[tid + i * 256] = g2[tid + i * 256];
        const float4* g3 = (const float4*)(pw1 + (size_t)ch * DH * DH);
        float4* l3 = (float4*)sPW1;
        #pragma unroll
        for (int i = 0; i < 4; ++i) l3[tid + i * 256] = g3[tid + i * 256];
        if (tid < DH) {
            sB2[tid]  = eb2[(size_t)ch * DH + tid];
            sPB1[tid] = pb1[(size_t)ch * DH + tid];
            sGW[tid]  = gw[(size_t)ch * DH + tid];
            sPW2[tid] = pw2[(size_t)ch * DH + tid];
        }
    }
    __syncthreads();

    const int wl   = tid & 63;
    const int ck   = wl & 3;
    const int quad = wl >> 2;
    const int qedge = blockIdx.x * 256 + (tid >> 6) * 64 + quad * 4;

    f32x16 W128v;
    LOAD16(W128v, ew1 + (size_t)ch * (2 * DH + 1) * DH + (size_t)(2 * DH) * DH + ck * 16)

    const int4 s4 = *(const int4*)(ssrc + qedge);
    const int4 t4 = *(const int4*)(sdst + qedge);
    const int d_0 = t4.x, d_1 = t4.y, d_2 = t4.z, d_3 = t4.w;

    float rx0 = pos[3*s4.x+0]-pos[3*t4.x+0], ry0 = pos[3*s4.x+1]-pos[3*t4.x+1], rz0 = pos[3*s4.x+2]-pos[3*t4.x+2];
    float rx1 = pos[3*s4.y+0]-pos[3*t4.y+0], ry1 = pos[3*s4.y+1]-pos[3*t4.y+1], rz1 = pos[3*s4.y+2]-pos[3*t4.y+2];
    float rx2 = pos[3*s4.z+0]-pos[3*t4.z+0], ry2 = pos[3*s4.z+1]-pos[3*t4.z+1], rz2 = pos[3*s4.z+2]-pos[3*t4.z+2];
    float rx3 = pos[3*s4.w+0]-pos[3*t4.w+0], ry3 = pos[3*s4.w+1]-pos[3*t4.w+1], rz3 = pos[3*s4.w+2]-pos[3*t4.w+2];
    const float dd0 = rx0*rx0+ry0*ry0+rz0*rz0;
    const float dd1 = rx1*rx1+ry1*ry1+rz1*rz1;
    const float dd2 = rx2*rx2+ry2*ry2+rz2*rz2;
    const float dd3 = rx3*rx3+ry3*ry3+rz3*rz3;

    const float GB = gb[ch];
    const float* hsp_c = hsp + (size_t)ch * N * DH;
    const float* hdp_c = hdp + (size_t)ch * N * DH;

    // ---- m1 = silu(hsp[s] + hdp[t] + d2*w128) ----
    f32x16 A0, A1, A2, A3, T;
    LOAD16(A0, hsp_c + (size_t)s4.x * DH + ck*16)
    LOAD16(T,  hdp_c + (size_t)t4.x * DH + ck*16)  ADD16(A0, T)  FMAV(A0, W128v, dd0)
    LOAD16(A1, hsp_c + (size_t)s4.y * DH + ck*16)
    LOAD16(T,  hdp_c + (size_t)t4.y * DH + ck*16)  ADD16(A1, T)  FMAV(A1, W128v, dd1)
    LOAD16(A2, hsp_c + (size_t)s4.z * DH + ck*16)
    LOAD16(T,  hdp_c + (size_t)t4.z * DH + ck*16)  ADD16(A2, T)  FMAV(A2, W128v, dd2)
    LOAD16(A3, hsp_c + (size_t)s4.w * DH + ck*16)
    LOAD16(T,  hdp_c + (size_t)t4.w * DH + ck*16)  ADD16(A3, T)  FMAV(A3, W128v, dd3)
    SILU16(A0) SILU16(A1) SILU16(A2) SILU16(A3)

    // ---- m2 = silu(m1 @ W2 + B2) ----
    f32x16 B0v, B1v, B2v, B3v;
    { f32x16 bz; LOAD16(bz, sB2 + ck*16) B0v = bz; B1v = bz; B2v = bz; B3v = bz; }
    WBPHASE(sW2, 0, QB0, A0,A1,A2,A3, B0v,B1v,B2v,B3v)
    WBPHASE(sW2, 1, QB1, A0,A1,A2,A3, B0v,B1v,B2v,B3v)
    WBPHASE(sW2, 2, QB2, A0,A1,A2,A3, B0v,B1v,B2v,B3v)
    WBPHASE(sW2, 3, QB3, A0,A1,A2,A3, B0v,B1v,B2v,B3v)
    SILU16(B0v) SILU16(B1v) SILU16(B2v) SILU16(B3v)

    // ---- gate (quad reduce via DPP) ----
    {
        f32x16 GWv; LOAD16(GWv, sGW + ck*16)
        float g0 = 0.f, g1 = 0.f, g2 = 0.f, g3 = 0.f;
        DOTV(g0, B0v, GWv) DOTV(g1, B1v, GWv) DOTV(g2, B2v, GWv) DOTV(g3, B3v, GWv)
        g0 += QPERM(g0, QXOR1); g0 += QPERM(g0, QXOR2);
        g1 += QPERM(g1, QXOR1); g1 += QPERM(g1, QXOR2);
        g2 += QPERM(g2, QXOR1); g2 += QPERM(g2, QXOR2);
        g3 += QPERM(g3, QXOR1); g3 += QPERM(g3, QXOR2);
        const float ga0 = sigmoidf_(GB + g0), ga1 = sigmoidf_(GB + g1);
        const float ga2 = sigmoidf_(GB + g2), ga3 = sigmoidf_(GB + g3);
        MUL16(B0v, ga0) MUL16(B1v, ga1) MUL16(B2v, ga2) MUL16(B3v, ga3)
    }

    // ---- q = silu(m2 @ PW1 + PB1); p = q @ PW2 ----
    { f32x16 bz; LOAD16(bz, sPB1 + ck*16) A0 = bz; A1 = bz; A2 = bz; A3 = bz; }
    WBPHASE(sPW1, 0, QB0, B0v,B1v,B2v,B3v, A0,A1,A2,A3)
    WBPHASE(sPW1, 1, QB1, B0v,B1v,B2v,B3v, A0,A1,A2,A3)
    WBPHASE(sPW1, 2, QB2, B0v,B1v,B2v,B3v, A0,A1,A2,A3)
    WBPHASE(sPW1, 3, QB3, B0v,B1v,B2v,B3v, A0,A1,A2,A3)
    SILU16(A0) SILU16(A1) SILU16(A2) SILU16(A3)
    float p0 = 0.f, p1 = 0.f, p2 = 0.f, p3 = 0.f;
    {
        f32x16 PW2v; LOAD16(PW2v, sPW2 + ck*16)
        DOTV(p0, A0, PW2v) DOTV(p1, A1, PW2v) DOTV(p2, A2, PW2v) DOTV(p3, A3, PW2v)
        p0 += QPERM(p0, QXOR1); p0 += QPERM(p0, QXOR2);
        p1 += QPERM(p1, QXOR1); p1 += QPERM(p1, QXOR2);
        p2 += QPERM(p2, QXOR1); p2 += QPERM(p2, QXOR2);
        p3 += QPERM(p3, QXOR1); p3 += QPERM(p3, QXOR2);
    }
    float tx0 = fminf(fmaxf(rx0*p0, -2.f), 2.f), ty0 = fminf(fmaxf(ry0*p0, -2.f), 2.f), tz0 = fminf(fmaxf(rz0*p0, -2.f), 2.f);
    float tx1 = fminf(fmaxf(rx1*p1, -2.f), 2.f), ty1 = fminf(fmaxf(ry1*p1, -2.f), 2.f), tz1 = fminf(fmaxf(rz1*p1, -2.f), 2.f);
    float tx2 = fminf(fmaxf(rx2*p2, -2.f), 2.f), ty2 = fminf(fmaxf(ry2*p2, -2.f), 2.f), tz2 = fminf(fmaxf(rz2*p2, -2.f), 2.f);
    float tx3 = fminf(fmaxf(rx3*p3, -2.f), 2.f), ty3 = fminf(fmaxf(ry3*p3, -2.f), 2.f), tz3 = fminf(fmaxf(rz3*p3, -2.f), 2.f);

    // ---- in-lane suffix merge over my 4 sorted edges ----
    const float e01 = (d_0 == d_1) ? 1.f : 0.f;
    const float e12 = (d_1 == d_2) ? 1.f : 0.f;
    const float e23 = (d_2 == d_3) ? 1.f : 0.f;
    FMAV(B2v, B3v, e23) tx2 = fmaf(e23, tx3, tx2); ty2 = fmaf(e23, ty3, ty2); tz2 = fmaf(e23, tz3, tz2);
    FMAV(B1v, B2v, e12) tx1 = fmaf(e12, tx2, tx1); ty1 = fmaf(e12, ty2, ty1); tz1 = fmaf(e12, tz2, tz1);
    FMAV(B0v, B1v, e01) tx0 = fmaf(e01, tx1, tx0); ty0 = fmaf(e01, ty1, ty0); tz0 = fmaf(e01, tz1, tz0);
    const float full0 = e01 * e12 * e23;
    const float f1 = e12 * e23;
    const float f2 = e23;

    // ---- cross-quad chain scan ----
    f32x16 Pv = B0v;
    float ppx = tx0, ppy = ty0, ppz = tz0;
    float fullf = full0;
    int hk = d_0, tk = d_3;
    SCANSTEP(4) SCANSTEP(8) SCANSTEP(16) SCANSTEP(32)
    f32x16 Sv; SHFL16D(Sv, Pv, 4)
    float spx = __shfl_down(ppx, 4), spy = __shfl_down(ppy, 4), spz = __shfl_down(ppz, 4);
    const int g1hk = __shfl_down(d_0, 4);
    const float sf = (((wl + 4) < 64) && (d_3 == g1hk)) ? 1.f : 0.f;
    MUL16(Sv, sf) spx *= sf; spy *= sf; spz *= sf;

    const int pd = __shfl_up(d_3, 4);
    const bool h0 = (quad == 0) || (pd != d_0);
    const bool h1 = (e01 == 0.f);
    const bool h2 = (e12 == 0.f);
    const bool h3 = (e23 == 0.f);

#define FLUSH(COND, DJ, BV, F, TX, TY, TZ) \
    if (COND) { \
        float* ar = agg + ((size_t)ch * N + (DJ)) * DH + ck * 16; \
        atomicAdd(ar+0,  BV[0]+(F)*Sv[0]);   atomicAdd(ar+1,  BV[1]+(F)*Sv[1]); \
        atomicAdd(ar+2,  BV[2]+(F)*Sv[2]);   atomicAdd(ar+3,  BV[3]+(F)*Sv[3]); \
        atomicAdd(ar+4,  BV[4]+(F)*Sv[4]);   atomicAdd(ar+5,  BV[5]+(F)*Sv[5]); \
        atomicAdd(ar+6,  BV[6]+(F)*Sv[6]);   atomicAdd(ar+7,  BV[7]+(F)*Sv[7]); \
        atomicAdd(ar+8,  BV[8]+(F)*Sv[8]);   atomicAdd(ar+9,  BV[9]+(F)*Sv[9]); \
        atomicAdd(ar+10, BV[10]+(F)*Sv[10]); atomicAdd(ar+11, BV[11]+(F)*Sv[11]); \
        atomicAdd(ar+12, BV[12]+(F)*Sv[12]); atomicAdd(ar+13, BV[13]+(F)*Sv[13]); \
        atomicAdd(ar+14, BV[14]+(F)*Sv[14]); atomicAdd(ar+15, BV[15]+(F)*Sv[15]); \
        if (ck == 0) { \
            atomicAdd(&pos_acc[(DJ)*3+0], (TX)+(F)*spx); \
            atomicAdd(&pos_acc[(DJ)*3+1], (TY)+(F)*spy); \
            atomicAdd(&pos_acc[(DJ)*3+2], (TZ)+(F)*spz); } }

    FLUSH(h0, d_0, B0v, full0, tx0, ty0, tz0)
    FLUSH(h1, d_1, B1v, f1,    tx1, ty1, tz1)
    FLUSH(h2, d_2, B2v, f2,    tx2, ty2, tz2)
    FLUSH(h3, d_3, B3v, 1.0f,  tx3, ty3, tz3)
#undef FLUSH
}

// ---------------- fused_out: node update + mix_out for 8 nodes ----------------
__global__ __launch_bounds__(256) void fused_out_kernel(
        const float* __restrict__ h, const float* __restrict__ agg,
        const float* __restrict__ nw, const float* __restrict__ nb,
        const float* __restrict__ Wout,
        float* __restrict__ x, int N) {
    __shared__ float hl[8][CC * DH];   // 8 KB
    __shared__ float al[8][CC * DH];   // 8 KB
    __shared__ float ol[8][CC * DH];   // 8 KB
    const int i0 = blockIdx.x * 8;
    const int tid = threadIdx.x;
    const int c = tid >> 6, d = tid & 63;

    for (int t = tid; t < 8 * CC * DH; t += 256) {
        int j = t >> 8, cd = t & 255;
        int cc = cd >> 6, dd = cd & 63;
        int i = i0 + j;
        if (i < N) {
            hl[j][cd] = h[((size_t)cc * N + i) * DH + dd];
            al[j][cd] = agg[((size_t)cc * N + i) * DH + dd];
        } else {
            hl[j][cd] = 0.f;
            al[j][cd] = 0.f;
        }
    }
    __syncthreads();

    {
        const float* W = nw + (size_t)c * (2 * DH) * DH;
        const float bn = nb[(size_t)c * DH + d];
        float acc[8] = {bn, bn, bn, bn, bn, bn, bn, bn};
        #pragma unroll 4
        for (int k = 0; k < DH; ++k) {
            const float w_h = W[(size_t)k * DH + d];
            const float w_a = W[(size_t)(DH + k) * DH + d];
            #pragma unroll
            for (int j = 0; j < 8; ++j) {
                acc[j] += hl[j][c * DH + k] * w_h + al[j][c * DH + k] * w_a;
            }
        }
        #pragma unroll
        for (int j = 0; j < 8; ++j) ol[j][tid] = acc[j];
    }
    __syncthreads();

    const int o = tid & 127, g = tid >> 7;
    float acc[4] = {0.f, 0.f, 0.f, 0.f};
    for (int cd = 0; cd < CC * DH; ++cd) {
        float w = Wout[(size_t)cd * DIN + o];
        #pragma unroll
        for (int j = 0; j < 4; ++j) acc[j] += ol[g * 4 + j][cd] * w;
    }
    #pragma unroll
    for (int j = 0; j < 4; ++j) {
        int i = i0 + g * 4 + j;
        if (i < N) x[(size_t)i * DIN + o] += acc[j];
    }
}

// ---------------- pos finalize ----------------
__global__ void pos_fin_kernel(float* __restrict__ pos, const float* __restrict__ pos_acc,
                               const int* __restrict__ cnt, int N) {
    int i = blockIdx.x * 256 + threadIdx.x;
    if (i < N) {
        float inv = 1.0f / ((float)CC * fmaxf((float)cnt[i], 1.0f));
        pos[i * 3 + 0] += pos_acc[i * 3 + 0] * inv;
        pos[i * 3 + 1] += pos_acc[i * 3 + 1] * inv;
        pos[i * 3 + 2] += pos_acc[i * 3 + 2] * inv;
    }
}

extern "C" void kernel_launch(void* const* d_in, const int* in_sizes, int n_in,
                              void* d_out, int out_size, void* d_ws, size_t ws_size,
                              hipStream_t stream) {
    const float* x         = (const float*)d_in[0];
    const float* pos       = (const float*)d_in[1];
    const int*   ei        = (const int*)d_in[2];
    const float* mix_in_w  = (const float*)d_in[3];
    const float* mix_out_w = (const float*)d_in[4];
    const float* ew1       = (const float*)d_in[5];
    const float* eb1       = (const float*)d_in[6];
    const float* ew2       = (const float*)d_in[7];
    const float* eb2       = (const float*)d_in[8];
    const float* gw        = (const float*)d_in[9];
    const float* gb        = (const float*)d_in[10];
    const float* nw        = (const float*)d_in[11];
    const float* nb        = (const float*)d_in[12];
    const float* pw1       = (const float*)d_in[13];
    const float* pb1       = (const float*)d_in[14];
    const float* pw2       = (const float*)d_in[15];

    const int* src = ei;
    const int* dst = ei + EE;

    float* xout    = (float*)d_out;
    float* pos_out = xout + (size_t)NN * DIN;

    float* hbuf    = (float*)d_ws;                     // C*N*64
    float* aggb    = hbuf + (size_t)CC * NN * DH;      // C*N*64
    float* hsp     = aggb + (size_t)CC * NN * DH;      // C*N*64
    float* hdp     = hsp  + (size_t)CC * NN * DH;      // C*N*64
    float* pos_cur = hdp  + (size_t)CC * NN * DH;      // N*3
    float* pos_acc = pos_cur + (size_t)NN * 3;         // N*3
    int*   cnt_i   = (int*)(pos_acc + (size_t)NN * 3); // N
    int*   offs    = cnt_i + NN;                       // N
    int*   fill    = offs + NN;                        // N
    int*   bsum    = fill + NN;                        // 256
    int*   ssrc    = bsum + 256;                       // E
    int*   sdst    = ssrc + EE;                        // E

    const int NB = (NN + 255) / 256;

    hipMemcpyAsync(xout, x, sizeof(float) * NN * DIN, hipMemcpyDeviceToDevice, stream);
    hipMemcpyAsync(pos_cur, pos, sizeof(float) * NN * 3, hipMemcpyDeviceToDevice, stream);
    hipMemsetAsync(cnt_i, 0, sizeof(int) * NN, stream);
    hipMemsetAsync(fill, 0, sizeof(int) * NN, stream);

    cnt_kernel<<<(EE + 255) / 256, 256, 0, stream>>>(dst, cnt_i, EE);
    scan1<<<NB, 256, 0, stream>>>(cnt_i, offs, bsum, NN);
    scan2<<<1, 256, 0, stream>>>(bsum, NB);
    scan3<<<NB, 256, 0, stream>>>(offs, bsum, NN);
    order_kernel<<<(EE + 255) / 256, 256, 0, stream>>>(src, dst, offs, fill, ssrc, sdst, EE);

    for (int l = 0; l < LL; ++l) {
        hipMemsetAsync(aggb, 0, sizeof(float) * CC * NN * DH, stream);
        hipMemsetAsync(pos_acc, 0, sizeof(float) * NN * 3, stream);

        fused_in_kernel<<<(NN + 7) / 8, 256, 0, stream>>>(
            xout, mix_in_w + (size_t)l * DIN * CC * DH,
            ew1 + (size_t)l * CC * (2 * DH + 1) * DH,
            eb1 + (size_t)l * CC * DH,
            hbuf, hsp, hdp, NN);

        edge_kernel<<<dim3(EE / 256, CC), 256, 0, stream>>>(
            hsp, hdp, pos_cur, ssrc, sdst,
            ew1 + (size_t)l * CC * (2 * DH + 1) * DH,
            ew2 + (size_t)l * CC * DH * DH,
            eb2 + (size_t)l * CC * DH,
            gw  + (size_t)l * CC * DH,
            gb  + (size_t)l * CC,
            pw1 + (size_t)l * CC * DH * DH,
            pb1 + (size_t)l * CC * DH,
            pw2 + (size_t)l * CC * DH,
            aggb, pos_acc, EE, NN);

        fused_out_kernel<<<(NN + 7) / 8, 256, 0, stream>>>(
            hbuf, aggb,
            nw + (size_t)l * CC * 2 * DH * DH,
            nb + (size_t)l * CC * DH,
            mix_out_w + (size_t)l * CC * DH * DIN,
            xout, NN);

        pos_fin_kernel<<<(NN + 255) / 256, 256, 0, stream>>>(pos_cur, pos_acc, cnt_i, NN);
    }

    hipMemcpyAsync(pos_out, pos_cur, sizeof(float) * NN * 3, hipMemcpyDeviceToDevice, stream);
}